// Round 4
// baseline (5253.546 us; speedup 1.0000x reference)
//
#include <hip/hip_runtime.h>
#include <hip/hip_bf16.h>

typedef unsigned int u32;
typedef _Float16     f16;
typedef f16   f16x8v __attribute__((ext_vector_type(8)));
typedef float f32x4  __attribute__((ext_vector_type(4)));

#define GX_BYTES ((size_t)65536 * 1024 * 2)

__device__ __forceinline__ float sigm(float x) {
    return __builtin_amdgcn_rcpf(1.0f + __expf(-x));
}
__device__ __forceinline__ float tanh_f(float x) {
    return 1.0f - 2.0f * __builtin_amdgcn_rcpf(__expf(2.0f * x) + 1.0f);
}
__device__ __forceinline__ f16x8v pack8(float4 a, float4 b) {
    f16x8v v;
    v[0] = (f16)a.x; v[1] = (f16)a.y; v[2] = (f16)a.z; v[3] = (f16)a.w;
    v[4] = (f16)b.x; v[5] = (f16)b.y; v[6] = (f16)b.z; v[7] = (f16)b.w;
    return v;
}

// ---------------------------------------------------------------------------
// Kernel 1: gates_x = x @ Wg[:, :256]^T + bg  -> f16 [65536][1024]
// (unchanged — plus zeroing the 256 KB mailbox each replay so stale tags
//  can never satisfy this run's polls)
// ---------------------------------------------------------------------------
__global__ __launch_bounds__(256) void gemm_gx(
    const float* __restrict__ X,
    const float* __restrict__ Wf, const float* __restrict__ Wi,
    const float* __restrict__ Wc, const float* __restrict__ Wo,
    const float* __restrict__ bf_, const float* __restrict__ bi_,
    const float* __restrict__ bc_, const float* __restrict__ bo_,
    f16* __restrict__ gx, u32* __restrict__ hx) {
    __shared__ _Float16 As[128 * 40];
    __shared__ _Float16 Bs[128 * 40];
    __shared__ float bias_lds[128];

    const int tid = threadIdx.x;
    const int wgy = blockIdx.y;
    const size_t m0 = (size_t)blockIdx.x * 128;

    if (wgy == 0) {
        const int gid = blockIdx.x * 256 + tid;
        if (gid < 16384) {
            int4 z; z.x = 0; z.y = 0; z.z = 0; z.w = 0;
            ((int4*)hx)[gid] = z;
        }
    }

    const float* Wsel[4] = {Wf, Wi, Wc, Wo};
    const float* bsel[4] = {bf_, bi_, bc_, bo_};
    const float* Wseg = Wsel[wgy >> 1];
    const int row_off = (wgy & 1) * 128;

    if (tid < 128) bias_lds[tid] = bsel[wgy >> 1][row_off + tid];

    const int r  = tid >> 2;
    const int c8 = (tid & 3) * 8;

    const float* Ap0 = X + (m0 + r) * 256 + c8;
    const float* Ap1 = Ap0 + 64 * 256;
    const float* Bp0 = Wseg + (size_t)(row_off + r) * 512 + c8;
    const float* Bp1 = Bp0 + 64 * 512;

    const int lane = tid & 63;
    const int w    = tid >> 6;
    const int wm = w >> 1, wn = w & 1;
    const int col = lane & 15, quad = lane >> 4;

    f32x4 acc[4][4] = {};

    for (int kc = 0; kc < 8; kc++) {
        const int kk = kc * 32;
        float4 a00 = *(const float4*)(Ap0 + kk);
        float4 a01 = *(const float4*)(Ap0 + kk + 4);
        float4 a10 = *(const float4*)(Ap1 + kk);
        float4 a11 = *(const float4*)(Ap1 + kk + 4);
        float4 b00 = *(const float4*)(Bp0 + kk);
        float4 b01 = *(const float4*)(Bp0 + kk + 4);
        float4 b10 = *(const float4*)(Bp1 + kk);
        float4 b11 = *(const float4*)(Bp1 + kk + 4);
        __syncthreads();
        *(f16x8v*)&As[r * 40 + c8]        = pack8(a00, a01);
        *(f16x8v*)&As[(r + 64) * 40 + c8] = pack8(a10, a11);
        *(f16x8v*)&Bs[r * 40 + c8]        = pack8(b00, b01);
        *(f16x8v*)&Bs[(r + 64) * 40 + c8] = pack8(b10, b11);
        __syncthreads();
        f16x8v a[4], b[4];
        #pragma unroll
        for (int i = 0; i < 4; i++)
            a[i] = *(const f16x8v*)&As[(wm * 64 + i * 16 + col) * 40 + quad * 8];
        #pragma unroll
        for (int j = 0; j < 4; j++)
            b[j] = *(const f16x8v*)&Bs[(wn * 64 + j * 16 + col) * 40 + quad * 8];
        #pragma unroll
        for (int i = 0; i < 4; i++)
            #pragma unroll
            for (int j = 0; j < 4; j++)
                acc[i][j] = __builtin_amdgcn_mfma_f32_16x16x32_f16(a[i], b[j], acc[i][j], 0, 0, 0);
    }

    #pragma unroll
    for (int i = 0; i < 4; i++) {
        #pragma unroll
        for (int j = 0; j < 4; j++) {
            #pragma unroll
            for (int rg = 0; rg < 4; rg++) {
                const size_t m = m0 + wm * 64 + i * 16 + quad * 4 + rg;
                const int nl = wn * 64 + j * 16 + col;
                gx[m * 1024 + (size_t)wgy * 128 + nl] = (f16)(acc[i][j][rg] + bias_lds[nl]);
            }
        }
    }
}

// ---------------------------------------------------------------------------
// Kernel 2: pairwise recurrence (round-1 skeleton) + K-split pipeline +
// early-issued poll. 256 WGs x 512 thr. WG (b = blk&127, s = blk>>7) owns
// units [128s,128s+128); wave w owns 16 units x 4 gates, weights fully
// register-resident (wB[4][8] = 128 VGPR). Pair (b, b+128) -> same XCD
// under round-robin (perf only; agent scope keeps it correct anywhere).
//
// Per step: gates = H_own @ W[:,Kown] (phase A, no remote dep) +
// H_rem @ W[:,Krem] (phase B). The partner-word load is ISSUED at the top
// of the step and only CHECKED after phase A — the ~700 cyc LLC round trip
// (rounds 2/3 lesson: agent atomics are LLC-serviced) hides under phase A's
// MFMAs; common case is zero exposed poll latency. Tight spin on mismatch
// (no s_sleep — round-3 lesson: sleep quantization serializes the step).
//
// Mailbox: [b][s][slot][128] tagged words (h<<16)|(t+1), relaxed agent
// atomics, 2-slot double buffer, same reuse induction as before; zeroed
// each replay by gemm_gx (tags 1..512 never match a stale run); spin
// bounded so a bug can't hang. h LDS double-buffered -> 2 barriers/step.
// Final h_512 completed by one extra tag-512 poll after the loop.
// ---------------------------------------------------------------------------
__global__ __launch_bounds__(512, 2) void lstm_rec(
    const float* __restrict__ Wf, const float* __restrict__ Wi,
    const float* __restrict__ Wc, const float* __restrict__ Wo,
    const f16* __restrict__ gx,
    const float* __restrict__ Wout, const float* __restrict__ bout,
    u32* hx,
    float* __restrict__ out) {
    __shared__ _Float16 hbuf[2][256] __attribute__((aligned(16)));

    const int tid  = threadIdx.x;
    const int bb   = blockIdx.x;
    const int b    = bb & 127;          // batch
    const int s    = bb >> 7;           // unit-half 0/1
    const int w    = tid >> 6;          // wave 0..7
    const int l    = tid & 63;
    const int l15  = l & 15;
    const int quad = l >> 4;

    const int u_loc = 16 * w + l15;     // 0..127 within our half
    const int u     = 128 * s + u_loc;  // absolute unit

    // --- register-resident B fragments: wB[g][kt] covers full K=256 ---
    f16x8v wB[4][8];
    {
        const float* gp[4] = {Wf, Wi, Wc, Wo};
        #pragma unroll
        for (int g = 0; g < 4; g++) {
            const float* row = gp[g] + (size_t)u * 512 + 256 + quad * 8;
            #pragma unroll
            for (int kt = 0; kt < 8; kt++) {
                float4 x0 = *(const float4*)(row + kt * 32);
                float4 x1 = *(const float4*)(row + kt * 32 + 4);
                wB[g][kt] = pack8(x0, x1);
            }
        }
    }

    float c = 0.0f;
    if (tid < 256) hbuf[0][tid] = (f16)0.0f;   // h_0 = 0 (both halves)

    u32* pub = hx + (size_t)b * 512 + (size_t)s * 256;        // + slot*128 + u_loc
    u32* par = hx + (size_t)b * 512 + (size_t)(1 - s) * 256;  // partner's words

    const f16* gxr = gx + (size_t)b * 512 * 1024 + u;
    float pf  = (float)gxr[0];
    float pi_ = (float)gxr[256];
    float pg  = (float)gxr[512];
    float po  = (float)gxr[768];

    const int ktA = 4 * s;          // own-K tiles
    const int ktB = 4 * (1 - s);    // remote-K tiles
    const int rbase = 128 * (1 - s);

    const f32x4 Zc = {0.f, 0.f, 0.f, 0.f};

    __syncthreads();   // h_0 visible

    for (int t = 0; t < 512; t++) {
        const int cur = t & 1;
        const int nxt = cur ^ 1;

        // 1. EARLY-ISSUE the partner-word load (checked after phase A).
        //    All lanes load (4x redundant per word) — keeps it branch-free
        //    in the main block so the scheduler hoists it before the MFMAs.
        u32 rw = __hip_atomic_load(par + cur * 128 + u_loc,
                                   __ATOMIC_RELAXED, __HIP_MEMORY_SCOPE_AGENT);

        // 2. gx prefetch for next step (used next iteration)
        float pnf, pni, png, pno;
        {
            const f16* gn = gxr + (size_t)(t < 511 ? t + 1 : 511) * 1024;
            pnf = (float)gn[0];
            pni = (float)gn[256];
            png = (float)gn[512];
            pno = (float)gn[768];
        }

        // 3. Phase A: own-K contribution (no remote dependence)
        f32x4 acc[4];
        #pragma unroll
        for (int k = 0; k < 4; k++) {
            f16x8v A = *(const f16x8v*)&hbuf[cur][(ktA + k) * 32 + quad * 8];
            if (k == 0) {
                #pragma unroll
                for (int g = 0; g < 4; g++)
                    acc[g] = __builtin_amdgcn_mfma_f32_16x16x32_f16(A, wB[g][ktA], Zc, 0, 0, 0);
            } else {
                #pragma unroll
                for (int g = 0; g < 4; g++)
                    acc[g] = __builtin_amdgcn_mfma_f32_16x16x32_f16(A, wB[g][ktA + k], acc[g], 0, 0, 0);
            }
        }

        // 4. Check the early load; tight per-lane spin only on mismatch.
        if (t > 0) {
            const u32 want = (u32)t;
            int spin = 0;
            while ((rw & 0xFFFFu) != want && ++spin < (1 << 20))
                rw = __hip_atomic_load(par + cur * 128 + u_loc,
                                       __ATOMIC_RELAXED, __HIP_MEMORY_SCOPE_AGENT);
            if (quad == 0)
                hbuf[cur][rbase + u_loc] =
                    __builtin_bit_cast(_Float16, (unsigned short)(rw >> 16));
        }
        __syncthreads();   // remote half of h_t staged

        // 5. Phase B: remote-K contribution
        #pragma unroll
        for (int k = 0; k < 4; k++) {
            f16x8v A = *(const f16x8v*)&hbuf[cur][(ktB + k) * 32 + quad * 8];
            #pragma unroll
            for (int g = 0; g < 4; g++)
                acc[g] = __builtin_amdgcn_mfma_f32_16x16x32_f16(A, wB[g][ktB + k], acc[g], 0, 0, 0);
        }

        // 6. Elementwise (rows replicated -> reg 0 is this lane's unit)
        float F = pf + acc[0][0];
        float I = pi_ + acc[1][0];
        float G = pg + acc[2][0];
        float O = po + acc[3][0];
        float sf = sigm(F), si = sigm(I), so = sigm(O);
        float tg = tanh_f(G);
        c = c * sf + si * tg;
        float h = tanh_f(c) * so;

        const f16 h16v = (f16)h;
        if (quad == 0) {
            u32 word = ((u32)__builtin_bit_cast(unsigned short, h16v) << 16)
                     | (u32)(t + 1);
            __hip_atomic_store(pub + nxt * 128 + u_loc, word,
                               __ATOMIC_RELAXED, __HIP_MEMORY_SCOPE_AGENT);
            hbuf[nxt][u] = h16v;    // own half for next step
        }

        pf = pnf; pi_ = pni; pg = png; po = pno;

        __syncthreads();   // own half of h_{t+1} visible; guards hbuf reuse
    }

    // Complete h_512: own half is in hbuf[0]; poll partner's tag-512 words.
    {
        u32 rw = __hip_atomic_load(par + 0 * 128 + u_loc,
                                   __ATOMIC_RELAXED, __HIP_MEMORY_SCOPE_AGENT);
        int spin = 0;
        while ((rw & 0xFFFFu) != 512u && ++spin < (1 << 20))
            rw = __hip_atomic_load(par + 0 * 128 + u_loc,
                                   __ATOMIC_RELAXED, __HIP_MEMORY_SCOPE_AGENT);
        if (quad == 0)
            hbuf[0][rbase + u_loc] =
                __builtin_bit_cast(_Float16, (unsigned short)(rw >> 16));
    }
    __syncthreads();

    // out[b, 64s:64s+64] = h_512 @ Wout^T + bout (both WGs have full h_512)
    if (tid < 64) {
        const int o = 64 * s + tid;
        float accv = bout[o];
        const float4* wv = (const float4*)(Wout + (size_t)o * 256);
        #pragma unroll
        for (int q = 0; q < 64; q++) {
            float4 v = wv[q];
            accv += v.x * (float)hbuf[0][q * 4 + 0];
            accv += v.y * (float)hbuf[0][q * 4 + 1];
            accv += v.z * (float)hbuf[0][q * 4 + 2];
            accv += v.w * (float)hbuf[0][q * 4 + 3];
        }
        out[(size_t)b * 128 + o] = accv;
    }
}

extern "C" void kernel_launch(void* const* d_in, const int* in_sizes, int n_in,
                              void* d_out, int out_size, void* d_ws, size_t ws_size,
                              hipStream_t stream) {
    const float* x    = (const float*)d_in[0];
    const float* Wf   = (const float*)d_in[1];
    const float* bfv  = (const float*)d_in[2];
    const float* Wi   = (const float*)d_in[3];
    const float* biv  = (const float*)d_in[4];
    const float* Wc   = (const float*)d_in[5];
    const float* bcv  = (const float*)d_in[6];
    const float* Wo   = (const float*)d_in[7];
    const float* bov  = (const float*)d_in[8];
    const float* Wout = (const float*)d_in[9];
    const float* bout = (const float*)d_in[10];

    f16* gx = (f16*)d_ws;
    u32* hx = (u32*)((char*)d_ws + GX_BYTES);   // 256 KB mailbox after gx

    gemm_gx<<<dim3(512, 8), 256, 0, stream>>>(x, Wf, Wi, Wc, Wo, bfv, biv, bcv, bov, gx, hx);
    lstm_rec<<<256, 512, 0, stream>>>(Wf, Wi, Wc, Wo, gx, Wout, bout, hx, (float*)d_out);
}

// Round 5
// 728.593 us; speedup vs baseline: 7.2105x; 7.2105x over previous
//
#include <hip/hip_runtime.h>
#include <hip/hip_bf16.h>

typedef unsigned int u32;
typedef _Float16     f16;
typedef f16   f16x8v __attribute__((ext_vector_type(8)));
typedef float f32x4  __attribute__((ext_vector_type(4)));

#define GX_BYTES ((size_t)65536 * 1024 * 2)

__device__ __forceinline__ float sigm(float x) {
    return __builtin_amdgcn_rcpf(1.0f + __expf(-x));
}
__device__ __forceinline__ float tanh_f(float x) {
    return 1.0f - 2.0f * __builtin_amdgcn_rcpf(__expf(2.0f * x) + 1.0f);
}
__device__ __forceinline__ f16x8v pack8(float4 a, float4 b) {
    f16x8v v;
    v[0] = (f16)a.x; v[1] = (f16)a.y; v[2] = (f16)a.z; v[3] = (f16)a.w;
    v[4] = (f16)b.x; v[5] = (f16)b.y; v[6] = (f16)b.z; v[7] = (f16)b.w;
    return v;
}

// ---------------------------------------------------------------------------
// Kernel 1: gates_x = x @ Wg[:, :256]^T + bg  -> f16 [65536][1024]
// (unchanged — plus zeroing the 256 KB mailbox each replay so stale tags
//  can never satisfy this run's polls)
// ---------------------------------------------------------------------------
__global__ __launch_bounds__(256) void gemm_gx(
    const float* __restrict__ X,
    const float* __restrict__ Wf, const float* __restrict__ Wi,
    const float* __restrict__ Wc, const float* __restrict__ Wo,
    const float* __restrict__ bf_, const float* __restrict__ bi_,
    const float* __restrict__ bc_, const float* __restrict__ bo_,
    f16* __restrict__ gx, u32* __restrict__ hx) {
    __shared__ _Float16 As[128 * 40];
    __shared__ _Float16 Bs[128 * 40];
    __shared__ float bias_lds[128];

    const int tid = threadIdx.x;
    const int wgy = blockIdx.y;
    const size_t m0 = (size_t)blockIdx.x * 128;

    if (wgy == 0) {
        const int gid = blockIdx.x * 256 + tid;
        if (gid < 16384) {
            int4 z; z.x = 0; z.y = 0; z.z = 0; z.w = 0;
            ((int4*)hx)[gid] = z;
        }
    }

    const float* Wsel[4] = {Wf, Wi, Wc, Wo};
    const float* bsel[4] = {bf_, bi_, bc_, bo_};
    const float* Wseg = Wsel[wgy >> 1];
    const int row_off = (wgy & 1) * 128;

    if (tid < 128) bias_lds[tid] = bsel[wgy >> 1][row_off + tid];

    const int r  = tid >> 2;
    const int c8 = (tid & 3) * 8;

    const float* Ap0 = X + (m0 + r) * 256 + c8;
    const float* Ap1 = Ap0 + 64 * 256;
    const float* Bp0 = Wseg + (size_t)(row_off + r) * 512 + c8;
    const float* Bp1 = Bp0 + 64 * 512;

    const int lane = tid & 63;
    const int w    = tid >> 6;
    const int wm = w >> 1, wn = w & 1;
    const int col = lane & 15, quad = lane >> 4;

    f32x4 acc[4][4] = {};

    for (int kc = 0; kc < 8; kc++) {
        const int kk = kc * 32;
        float4 a00 = *(const float4*)(Ap0 + kk);
        float4 a01 = *(const float4*)(Ap0 + kk + 4);
        float4 a10 = *(const float4*)(Ap1 + kk);
        float4 a11 = *(const float4*)(Ap1 + kk + 4);
        float4 b00 = *(const float4*)(Bp0 + kk);
        float4 b01 = *(const float4*)(Bp0 + kk + 4);
        float4 b10 = *(const float4*)(Bp1 + kk);
        float4 b11 = *(const float4*)(Bp1 + kk + 4);
        __syncthreads();
        *(f16x8v*)&As[r * 40 + c8]        = pack8(a00, a01);
        *(f16x8v*)&As[(r + 64) * 40 + c8] = pack8(a10, a11);
        *(f16x8v*)&Bs[r * 40 + c8]        = pack8(b00, b01);
        *(f16x8v*)&Bs[(r + 64) * 40 + c8] = pack8(b10, b11);
        __syncthreads();
        f16x8v a[4], b[4];
        #pragma unroll
        for (int i = 0; i < 4; i++)
            a[i] = *(const f16x8v*)&As[(wm * 64 + i * 16 + col) * 40 + quad * 8];
        #pragma unroll
        for (int j = 0; j < 4; j++)
            b[j] = *(const f16x8v*)&Bs[(wn * 64 + j * 16 + col) * 40 + quad * 8];
        #pragma unroll
        for (int i = 0; i < 4; i++)
            #pragma unroll
            for (int j = 0; j < 4; j++)
                acc[i][j] = __builtin_amdgcn_mfma_f32_16x16x32_f16(a[i], b[j], acc[i][j], 0, 0, 0);
    }

    #pragma unroll
    for (int i = 0; i < 4; i++) {
        #pragma unroll
        for (int j = 0; j < 4; j++) {
            #pragma unroll
            for (int rg = 0; rg < 4; rg++) {
                const size_t m = m0 + wm * 64 + i * 16 + quad * 4 + rg;
                const int nl = wn * 64 + j * 16 + col;
                gx[m * 1024 + (size_t)wgy * 128 + nl] = (f16)(acc[i][j][rg] + bias_lds[nl]);
            }
        }
    }
}

// ---------------------------------------------------------------------------
// Kernel 2: pairwise recurrence + K-split pipeline + early-issued poll.
// 256 WGs x 512 thr. WG (b = blk&127, s = blk>>7) owns units [128s,128s+128);
// wave w owns 16 units x 4 gates, weights fully register-resident.
//
// ROUND-4 FIX (rule #20): wB indices are now COMPILE-TIME ONLY.
// wB[g][0..3] = own-K tiles (h columns [128s,128s+128)), wB[g][4..7] =
// remote-K tiles — the runtime 's' lives in the LOAD ADDRESS and the LDS
// A-fragment offset (both fine), never in a register-array subscript.
// Round 4's wB[g][ktA+k] demoted all 32 fragments to scratch: VGPR=40,
// FETCH 17.4 GB (34 MB/step of scratch re-reads).
//
// Per step: phase A = own-K MFMAs (no remote dep) covers the LLC round
// trip of the partner-word load issued at the step top (agent atomics are
// LLC-serviced — rounds 2/3); the tag check lands after phase A, usually
// already satisfied. Tight spin on mismatch. Same proven mailbox protocol
// (tagged words, 2 slots, zeroed each replay, bounded spin).
// ---------------------------------------------------------------------------
__global__ __launch_bounds__(512, 2) void lstm_rec(
    const float* __restrict__ Wf, const float* __restrict__ Wi,
    const float* __restrict__ Wc, const float* __restrict__ Wo,
    const f16* __restrict__ gx,
    const float* __restrict__ Wout, const float* __restrict__ bout,
    u32* hx,
    float* __restrict__ out) {
    __shared__ _Float16 hbuf[2][256] __attribute__((aligned(16)));

    const int tid  = threadIdx.x;
    const int bb   = blockIdx.x;
    const int b    = bb & 127;          // batch
    const int s    = bb >> 7;           // unit-half 0/1
    const int w    = tid >> 6;          // wave 0..7
    const int l    = tid & 63;
    const int l15  = l & 15;
    const int quad = l >> 4;

    const int u_loc = 16 * w + l15;     // 0..127 within our half
    const int u     = 128 * s + u_loc;  // absolute unit

    const int kOwn = 128 * s;           // h-column base of own half
    const int kRem = 128 * (1 - s);     // h-column base of remote half

    // --- register-resident B fragments, STATIC indices:
    //     wB[g][0..3] own-K, wB[g][4..7] remote-K ---
    f16x8v wB[4][8];
    {
        const float* gp[4] = {Wf, Wi, Wc, Wo};
        #pragma unroll
        for (int g = 0; g < 4; g++) {
            const float* rowO = gp[g] + (size_t)u * 512 + 256 + kOwn + quad * 8;
            const float* rowR = gp[g] + (size_t)u * 512 + 256 + kRem + quad * 8;
            #pragma unroll
            for (int k = 0; k < 4; k++) {
                float4 x0 = *(const float4*)(rowO + k * 32);
                float4 x1 = *(const float4*)(rowO + k * 32 + 4);
                wB[g][k] = pack8(x0, x1);
                float4 y0 = *(const float4*)(rowR + k * 32);
                float4 y1 = *(const float4*)(rowR + k * 32 + 4);
                wB[g][4 + k] = pack8(y0, y1);
            }
        }
    }

    float c = 0.0f;
    if (tid < 256) hbuf[0][tid] = (f16)0.0f;   // h_0 = 0 (both halves)

    u32* pub = hx + (size_t)b * 512 + (size_t)s * 256;        // + slot*128 + u_loc
    u32* par = hx + (size_t)b * 512 + (size_t)(1 - s) * 256;  // partner's words

    const f16* gxr = gx + (size_t)b * 512 * 1024 + u;
    float pf  = (float)gxr[0];
    float pi_ = (float)gxr[256];
    float pg  = (float)gxr[512];
    float po  = (float)gxr[768];

    const f32x4 Zc = {0.f, 0.f, 0.f, 0.f};

    __syncthreads();   // h_0 visible

    for (int t = 0; t < 512; t++) {
        const int cur = t & 1;
        const int nxt = cur ^ 1;

        // 1. EARLY-ISSUE the partner-word load (checked after phase A).
        u32 rw = __hip_atomic_load(par + cur * 128 + u_loc,
                                   __ATOMIC_RELAXED, __HIP_MEMORY_SCOPE_AGENT);

        // 2. gx prefetch for next step
        float pnf, pni, png, pno;
        {
            const f16* gn = gxr + (size_t)(t < 511 ? t + 1 : 511) * 1024;
            pnf = (float)gn[0];
            pni = (float)gn[256];
            png = (float)gn[512];
            pno = (float)gn[768];
        }

        // 3. Phase A: own-K contribution (LDS offset runtime, reg idx static)
        const _Float16* hOwn = &hbuf[cur][kOwn + quad * 8];
        f32x4 acc[4];
        #pragma unroll
        for (int k = 0; k < 4; k++) {
            f16x8v A = *(const f16x8v*)&hOwn[k * 32];
            if (k == 0) {
                #pragma unroll
                for (int g = 0; g < 4; g++)
                    acc[g] = __builtin_amdgcn_mfma_f32_16x16x32_f16(A, wB[g][0], Zc, 0, 0, 0);
            } else {
                #pragma unroll
                for (int g = 0; g < 4; g++)
                    acc[g] = __builtin_amdgcn_mfma_f32_16x16x32_f16(A, wB[g][k], acc[g], 0, 0, 0);
            }
        }

        // 4. Check the early load; tight per-lane spin only on mismatch.
        if (t > 0) {
            const u32 want = (u32)t;
            int spin = 0;
            while ((rw & 0xFFFFu) != want && ++spin < (1 << 20))
                rw = __hip_atomic_load(par + cur * 128 + u_loc,
                                       __ATOMIC_RELAXED, __HIP_MEMORY_SCOPE_AGENT);
            if (quad == 0)
                hbuf[cur][kRem + u_loc] =
                    __builtin_bit_cast(_Float16, (unsigned short)(rw >> 16));
        }
        __syncthreads();   // remote half of h_t staged

        // 5. Phase B: remote-K contribution
        const _Float16* hRem = &hbuf[cur][kRem + quad * 8];
        #pragma unroll
        for (int k = 0; k < 4; k++) {
            f16x8v A = *(const f16x8v*)&hRem[k * 32];
            #pragma unroll
            for (int g = 0; g < 4; g++)
                acc[g] = __builtin_amdgcn_mfma_f32_16x16x32_f16(A, wB[g][4 + k], acc[g], 0, 0, 0);
        }

        // 6. Elementwise (rows replicated -> reg 0 is this lane's unit)
        float F = pf + acc[0][0];
        float I = pi_ + acc[1][0];
        float G = pg + acc[2][0];
        float O = po + acc[3][0];
        float sf = sigm(F), si = sigm(I), so = sigm(O);
        float tg = tanh_f(G);
        c = c * sf + si * tg;
        float h = tanh_f(c) * so;

        const f16 h16v = (f16)h;
        if (quad == 0) {
            u32 word = ((u32)__builtin_bit_cast(unsigned short, h16v) << 16)
                     | (u32)(t + 1);
            __hip_atomic_store(pub + nxt * 128 + u_loc, word,
                               __ATOMIC_RELAXED, __HIP_MEMORY_SCOPE_AGENT);
            hbuf[nxt][u] = h16v;    // own half for next step
        }

        pf = pnf; pi_ = pni; pg = png; po = pno;

        __syncthreads();   // own half of h_{t+1} visible; guards hbuf reuse
    }

    // Complete h_512: own half is in hbuf[0]; poll partner's tag-512 words.
    {
        u32 rw = __hip_atomic_load(par + 0 * 128 + u_loc,
                                   __ATOMIC_RELAXED, __HIP_MEMORY_SCOPE_AGENT);
        int spin = 0;
        while ((rw & 0xFFFFu) != 512u && ++spin < (1 << 20))
            rw = __hip_atomic_load(par + 0 * 128 + u_loc,
                                   __ATOMIC_RELAXED, __HIP_MEMORY_SCOPE_AGENT);
        if (quad == 0)
            hbuf[0][kRem + u_loc] =
                __builtin_bit_cast(_Float16, (unsigned short)(rw >> 16));
    }
    __syncthreads();

    // out[b, 64s:64s+64] = h_512 @ Wout^T + bout (both WGs have full h_512)
    if (tid < 64) {
        const int o = 64 * s + tid;
        float accv = bout[o];
        const float4* wv = (const float4*)(Wout + (size_t)o * 256);
        #pragma unroll
        for (int q = 0; q < 64; q++) {
            float4 v = wv[q];
            accv += v.x * (float)hbuf[0][q * 4 + 0];
            accv += v.y * (float)hbuf[0][q * 4 + 1];
            accv += v.z * (float)hbuf[0][q * 4 + 2];
            accv += v.w * (float)hbuf[0][q * 4 + 3];
        }
        out[(size_t)b * 128 + o] = accv;
    }
}

extern "C" void kernel_launch(void* const* d_in, const int* in_sizes, int n_in,
                              void* d_out, int out_size, void* d_ws, size_t ws_size,
                              hipStream_t stream) {
    const float* x    = (const float*)d_in[0];
    const float* Wf   = (const float*)d_in[1];
    const float* bfv  = (const float*)d_in[2];
    const float* Wi   = (const float*)d_in[3];
    const float* biv  = (const float*)d_in[4];
    const float* Wc   = (const float*)d_in[5];
    const float* bcv  = (const float*)d_in[6];
    const float* Wo   = (const float*)d_in[7];
    const float* bov  = (const float*)d_in[8];
    const float* Wout = (const float*)d_in[9];
    const float* bout = (const float*)d_in[10];

    f16* gx = (f16*)d_ws;
    u32* hx = (u32*)((char*)d_ws + GX_BYTES);   // 256 KB mailbox after gx

    gemm_gx<<<dim3(512, 8), 256, 0, stream>>>(x, Wf, Wi, Wc, Wo, bfv, biv, bcv, bov, gx, hx);
    lstm_rec<<<256, 512, 0, stream>>>(Wf, Wi, Wc, Wo, gx, Wout, bout, hx, (float*)d_out);
}